// Round 1
// baseline (7887.446 us; speedup 1.0000x reference)
//
#include <hip/hip_runtime.h>

#define NB 8
#define TT 24
#define NN 4000
#define FF 32
#define HH 128
#define GG 512
#define EE 64000
#define MT 16

__device__ __forceinline__ float fsig(float x) { return 1.0f / (1.0f + __expf(-x)); }
__device__ __forceinline__ float ftanh(float x) { float e = __expf(2.0f * x); return 1.0f - 2.0f / (e + 1.0f); }

// ---------- setup: pack weights, combine bias, init deg ----------
// Wp_hh packed: Wp[((k4*4+g)*128 + j)*4 + q] = W_hh[(g*128+j)*128 + k4*4+q]
// Wp_ih packed: Wp[((f4*4+g)*128 + j)*4 + q] = W_ih[(g*128+j)*32  + f4*4+q]
__global__ void setup_kernel(const float* __restrict__ W_ih, const float* __restrict__ W_hh,
                             const float* __restrict__ b_ih, const float* __restrict__ b_hh,
                             const float* __restrict__ gcn_W,
                             float* __restrict__ Wp_hh, float* __restrict__ Wp_ih,
                             float* __restrict__ gcn_WT, float* __restrict__ bias,
                             float* __restrict__ deg) {
  int idx = blockIdx.x * 256 + threadIdx.x;
  if (idx < 65536) {
    int q = idx & 3, j = (idx >> 2) & 127, g = (idx >> 9) & 3, k4 = idx >> 11;
    Wp_hh[idx] = W_hh[(g * 128 + j) * 128 + k4 * 4 + q];
  } else if (idx < 65536 + 16384) {
    int i2 = idx - 65536;
    int q = i2 & 3, j = (i2 >> 2) & 127, g = (i2 >> 9) & 3, f4 = i2 >> 11;
    Wp_ih[i2] = W_ih[(g * 128 + j) * 32 + f4 * 4 + q];
  } else if (idx < 65536 + 16384 + 16384) {
    int i2 = idx - 65536 - 16384;
    int g = i2 & 127, k = i2 >> 7;
    gcn_WT[i2] = gcn_W[g * 128 + k];
  } else if (idx < 65536 + 16384 + 16384 + 512) {
    int g = idx - (65536 + 16384 + 16384);
    bias[g] = b_ih[g] + b_hh[g];
  } else if (idx < 65536 + 16384 + 16384 + 512 + NN) {
    int n = idx - (65536 + 16384 + 16384 + 512);
    deg[n] = 1.0f;  // self-loop
  }
}

// ---------- LSTM: one block = 16 sequences, 128 threads (thread j = hidden col j) ----------
__global__ __launch_bounds__(128) void lstm_kernel(
    const float* __restrict__ x,       // [B,T,N,F]
    const float* __restrict__ Wp_ih,   // packed
    const float* __restrict__ Wp_hh,   // packed
    const float* __restrict__ bias,    // [512] combined
    float* __restrict__ h_out)         // [B*N, H]
{
  __shared__ float h_lds[MT][HH];
  __shared__ float x_lds[MT][FF];
  const int j = threadIdx.x;
  const int blk = blockIdx.x;
  const int b = blk / (NN / MT);
  const int n0 = (blk % (NN / MT)) * MT;

  for (int m = 0; m < MT; ++m) h_lds[m][j] = 0.0f;
  float c[MT];
#pragma unroll
  for (int m = 0; m < MT; ++m) c[m] = 0.0f;
  const float bi = bias[j], bf = bias[128 + j], bg = bias[256 + j], bo = bias[384 + j];

  const float4* __restrict__ wp = (const float4*)Wp_hh;
  const float4* __restrict__ wip = (const float4*)Wp_ih;
  __syncthreads();

  for (int t = 0; t < TT; ++t) {
    // issue x-tile load early (16 seq x 32 feat = 512 contiguous floats)
    const float4* xt = (const float4*)(x + (((size_t)b * TT + t) * NN + n0) * FF);
    float4 xv = xt[j];

    float ai[MT], af[MT], ag[MT], ao[MT];
#pragma unroll
    for (int m = 0; m < MT; ++m) { ai[m] = bi; af[m] = bf; ag[m] = bg; ao[m] = bo; }

    // recurrence: h(t-1) @ W_hh^T
#pragma unroll 2
    for (int k4 = 0; k4 < 32; ++k4) {
      float4 wi = wp[(k4 * 4 + 0) * 128 + j];
      float4 wf = wp[(k4 * 4 + 1) * 128 + j];
      float4 wg = wp[(k4 * 4 + 2) * 128 + j];
      float4 wo = wp[(k4 * 4 + 3) * 128 + j];
#pragma unroll
      for (int m = 0; m < MT; ++m) {
        float4 hv = *(const float4*)&h_lds[m][k4 * 4];
        ai[m] += hv.x * wi.x + hv.y * wi.y + hv.z * wi.z + hv.w * wi.w;
        af[m] += hv.x * wf.x + hv.y * wf.y + hv.z * wf.z + hv.w * wf.w;
        ag[m] += hv.x * wg.x + hv.y * wg.y + hv.z * wg.z + hv.w * wg.w;
        ao[m] += hv.x * wo.x + hv.y * wo.y + hv.z * wo.z + hv.w * wo.w;
      }
    }
    __syncthreads();                       // h reads done
    ((float4*)&x_lds[0][0])[j] = xv;       // stage x tile
    __syncthreads();

    // input projection: x(t) @ W_ih^T
#pragma unroll
    for (int f4 = 0; f4 < 8; ++f4) {
      float4 wi = wip[(f4 * 4 + 0) * 128 + j];
      float4 wf = wip[(f4 * 4 + 1) * 128 + j];
      float4 wg = wip[(f4 * 4 + 2) * 128 + j];
      float4 wo = wip[(f4 * 4 + 3) * 128 + j];
#pragma unroll
      for (int m = 0; m < MT; ++m) {
        float4 xr = *(const float4*)&x_lds[m][f4 * 4];
        ai[m] += xr.x * wi.x + xr.y * wi.y + xr.z * wi.z + xr.w * wi.w;
        af[m] += xr.x * wf.x + xr.y * wf.y + xr.z * wf.z + xr.w * wf.w;
        ag[m] += xr.x * wg.x + xr.y * wg.y + xr.z * wg.z + xr.w * wg.w;
        ao[m] += xr.x * wo.x + xr.y * wo.y + xr.z * wo.z + xr.w * wo.w;
      }
    }

    // gates (PyTorch order i,f,g,o)
#pragma unroll
    for (int m = 0; m < MT; ++m) {
      float iv = fsig(ai[m]);
      float fv = fsig(af[m]);
      float gv = ftanh(ag[m]);
      float ov = fsig(ao[m]);
      c[m] = fv * c[m] + iv * gv;
      float hh = ov * ftanh(c[m]);
      h_lds[m][j] = hh;
      if (t == TT - 1) h_out[((size_t)(b * NN + n0 + m)) * HH + j] = hh;
    }
    __syncthreads();
  }
}

// ---------- GCN ----------
__global__ void deg_kernel(const int* __restrict__ ei, float* __restrict__ deg) {
  int e = blockIdx.x * 256 + threadIdx.x;
  if (e < EE) atomicAdd(&deg[ei[EE + e]], 1.0f);  // dst row
}

__global__ void dinv_kernel(const float* __restrict__ deg, float* __restrict__ dinv) {
  int n = blockIdx.x * 256 + threadIdx.x;
  if (n < NN) dinv[n] = 1.0f / sqrtf(deg[n]);  // deg >= 1 (self loop)
}

// xw[b,n,g] = sum_k h[b,n,k] * gcn_W[g,k]  ; 8 rows per block
__global__ __launch_bounds__(128) void xw_kernel(const float* __restrict__ h,
                                                 const float* __restrict__ gcn_WT,
                                                 float* __restrict__ xw) {
  const int r0 = blockIdx.x * 8;
  const int g = threadIdx.x;
  __shared__ float hs[8][HH];
  for (int m = 0; m < 8; ++m) hs[m][g] = h[(size_t)(r0 + m) * HH + g];
  __syncthreads();
  float acc[8] = {0, 0, 0, 0, 0, 0, 0, 0};
#pragma unroll 4
  for (int k = 0; k < HH; ++k) {
    float w = gcn_WT[k * HH + g];
#pragma unroll
    for (int m = 0; m < 8; ++m) acc[m] += hs[m][k] * w;
  }
  for (int m = 0; m < 8; ++m) xw[(size_t)(r0 + m) * HH + g] = acc[m];
}

// scatter: agg[b,dst,:] += xw[b,src,:] * norm(e); thread = (edge, channel)
__global__ void scatter_kernel(const int* __restrict__ ei, const float* __restrict__ xw,
                               const float* __restrict__ dinv, float* __restrict__ agg) {
  int gid = blockIdx.x * 256 + threadIdx.x;
  int e = gid >> 7;
  int jj = gid & 127;
  if (e >= EE) return;
  int s = ei[e];
  int d = ei[EE + e];
  float nrm = dinv[s] * dinv[d];
#pragma unroll
  for (int b = 0; b < NB; ++b) {
    float v = xw[((size_t)b * NN + s) * HH + jj] * nrm;
    atomicAdd(&agg[((size_t)b * NN + d) * HH + jj], v);
  }
}

// final: add self-loop + bias, relu, two dot heads. one wave per row.
__global__ __launch_bounds__(256) void final_kernel(
    const float* __restrict__ agg, const float* __restrict__ xw, const float* __restrict__ dinv,
    const float* __restrict__ gcn_b, const float* __restrict__ fcw_c, const float* __restrict__ fcb_c,
    const float* __restrict__ fcw_i, const float* __restrict__ fcb_i, float* __restrict__ out) {
  int row = blockIdx.x * 4 + (threadIdx.x >> 6);
  int lane = threadIdx.x & 63;
  int n = row % NN;
  float sn = dinv[n] * dinv[n];
  float sc = 0.0f, si = 0.0f;
  for (int jj = lane; jj < HH; jj += 64) {
    float v = agg[(size_t)row * HH + jj] + xw[(size_t)row * HH + jj] * sn + gcn_b[jj];
    v = fmaxf(v, 0.0f);
    sc += v * fcw_c[jj];
    si += v * fcw_i[jj];
  }
#pragma unroll
  for (int off = 32; off > 0; off >>= 1) {
    sc += __shfl_down(sc, off);
    si += __shfl_down(si, off);
  }
  if (lane == 0) {
    out[row] = sc + fcb_c[0];
    out[NB * NN + row] = si + fcb_i[0];
  }
}

extern "C" void kernel_launch(void* const* d_in, const int* in_sizes, int n_in,
                              void* d_out, int out_size, void* d_ws, size_t ws_size,
                              hipStream_t stream) {
  const float* x     = (const float*)d_in[0];
  const int*   ei    = (const int*)d_in[1];
  const float* W_ih  = (const float*)d_in[2];
  const float* W_hh  = (const float*)d_in[3];
  const float* b_ih  = (const float*)d_in[4];
  const float* b_hh  = (const float*)d_in[5];
  const float* gcn_W = (const float*)d_in[6];
  const float* gcn_b = (const float*)d_in[7];
  const float* fcw_c = (const float*)d_in[8];
  const float* fcb_c = (const float*)d_in[9];
  const float* fcw_i = (const float*)d_in[10];
  const float* fcb_i = (const float*)d_in[11];
  float* out = (float*)d_out;

  float* ws     = (float*)d_ws;
  float* Wp_hh  = ws;                    // 65536
  float* Wp_ih  = Wp_hh + 65536;         // 16384
  float* gcn_WT = Wp_ih + 16384;         // 16384
  float* bias   = gcn_WT + 16384;        // 512
  float* deg    = bias + 512;            // 4000
  float* dinv   = deg + 4000;            // 4000
  float* h_all  = dinv + 4000;           // 4,096,000
  float* xw     = h_all + 4096000;       // 4,096,000
  float* agg    = xw + 4096000;          // 4,096,000

  setup_kernel<<<402, 256, 0, stream>>>(W_ih, W_hh, b_ih, b_hh, gcn_W,
                                        Wp_hh, Wp_ih, gcn_WT, bias, deg);
  hipMemsetAsync(agg, 0, (size_t)4096000 * sizeof(float), stream);
  lstm_kernel<<<(NB * NN) / MT, 128, 0, stream>>>(x, Wp_ih, Wp_hh, bias, h_all);
  deg_kernel<<<EE / 256, 256, 0, stream>>>(ei, deg);
  dinv_kernel<<<(NN + 255) / 256, 256, 0, stream>>>(deg, dinv);
  xw_kernel<<<(NB * NN) / 8, 128, 0, stream>>>(h_all, gcn_WT, xw);
  scatter_kernel<<<(EE * 128) / 256, 256, 0, stream>>>(ei, xw, dinv, agg);
  final_kernel<<<(NB * NN) / 4, 256, 0, stream>>>(agg, xw, dinv, gcn_b, fcw_c, fcb_c,
                                                  fcw_i, fcb_i, out);
}